// Round 6
// baseline (150.788 us; speedup 1.0000x reference)
//
#include <hip/hip_runtime.h>
#include <hip/hip_bf16.h>
#include <math.h>

// ---------------------------------------------------------------------------
// SentiGAT — round 5: stage A fully fused (one block per sample).
//  prep  : vvec + all weight transposes (unchanged)
//  fusedA: X -> scores/alpha -> z(LDS bf16) -> in-LDS MFMA GEMM (z @ Wc)
//          -> hout(LDS fp32) -> attn softmax -> aligned -> ind_norm -> x5b
//  C1/C3 : MFMA GEMMs, C2/C4: 5-node GAT, D1: split-K MFMA, D2: final proj
// ---------------------------------------------------------------------------

#define B_SAMP 512

typedef short short8 __attribute__((ext_vector_type(8)));
typedef float floatx4 __attribute__((ext_vector_type(4)));

__device__ __forceinline__ float lrelu02(float x) { return x > 0.f ? x : 0.2f * x; }

__device__ __forceinline__ unsigned short cvt_bf16(float f) {
    union { float f; unsigned int u; } v; v.f = f;
    unsigned int u = v.u;
    return (unsigned short)((u + 0x7FFFu + ((u >> 16) & 1u)) >> 16);  // RNE
}

// ---------------- merged prep: ow_vvec + all weight transposes --------------
__global__ __launch_bounds__(256) void prep(
    const float* __restrict__ ow_W, const float* __restrict__ ow_asrc,
    const float* __restrict__ ow_adst,
    const float* __restrict__ g1_W, const float* __restrict__ g2_W,
    const float* __restrict__ m1_W,
    float* __restrict__ vg, unsigned short* __restrict__ owWt,
    unsigned short* __restrict__ g1Wt, unsigned short* __restrict__ g2Wt,
    unsigned short* __restrict__ m1Wt)
{
    __shared__ float T[32][33];
    const int tid = threadIdx.x;
    int bid = blockIdx.x;

    if (bid < 128) {
        const int lane = tid & 63;
        const int gw = bid * 4 + (tid >> 6);
        for (int idx = gw; idx < 2048; idx += 512) {
            int t = idx >> 9, k = idx & 511;
            const float* a = (t < 2) ? (ow_asrc + t * 512) : (ow_adst + (t - 2) * 512);
            const float* wr = ow_W + (size_t)k * 1024 + (t & 1) * 512;
            float s = 0.f;
#pragma unroll
            for (int j = 0; j < 8; ++j) s += wr[lane + 64 * j] * a[lane + 64 * j];
            for (int off = 32; off > 0; off >>= 1) s += __shfl_down(s, off, 64);
            if (lane == 0) vg[idx] = s;
        }
        return;
    }
    bid -= 128;
    const float* W; int ldw, K, Kpad, koff, ktiles; float scale; unsigned short* Wt;
    if (bid < 256)        { W = ow_W;       ldw = 1024; K = 512;  Kpad = 1024; koff = 0;   scale = 0.5f; Wt = owWt; ktiles = 16; }
    else if (bid < 512)   { bid -= 256;  W = ow_W + 512; ldw = 1024; K = 512;  Kpad = 1024; koff = 512; scale = 0.5f; Wt = owWt; ktiles = 16; }
    else if (bid < 784)   { bid -= 512;  W = g1_W; ldw = 512; K = 513;  Kpad = 544;  koff = 0; scale = 1.f; Wt = g1Wt; ktiles = 17; }
    else if (bid < 1040)  { bid -= 784;  W = g2_W; ldw = 512; K = 512;  Kpad = 512;  koff = 0; scale = 1.f; Wt = g2Wt; ktiles = 16; }
    else                  { bid -= 1040; W = m1_W; ldw = 512; K = 2560; Kpad = 2560; koff = 0; scale = 1.f; Wt = m1Wt; ktiles = 80; }
    const int k0 = (bid % ktiles) * 32;
    const int n0 = (bid / ktiles) * 32;
    {
        int kr = tid >> 3, nc = (tid & 7) * 4;
        float4 v = make_float4(0.f, 0.f, 0.f, 0.f);
        if (k0 + kr < K) v = *(const float4*)(W + (size_t)(k0 + kr) * ldw + n0 + nc);
        T[nc + 0][kr] = v.x * scale; T[nc + 1][kr] = v.y * scale;
        T[nc + 2][kr] = v.z * scale; T[nc + 3][kr] = v.w * scale;
    }
    __syncthreads();
    {
        int nr = tid >> 3, kc = (tid & 7) * 4;
        ushort4 w;
        w.x = cvt_bf16(T[nr][kc + 0]);
        w.y = cvt_bf16(T[nr][kc + 1]);
        w.z = cvt_bf16(T[nr][kc + 2]);
        w.w = cvt_bf16(T[nr][kc + 3]);
        *(ushort4*)(Wt + (size_t)(n0 + nr) * Kpad + koff + k0 + kc) = w;
    }
}

// ---------------- fusedA: one block per sample ------------------------------
// LDS: Xs[28][516] f32 (57792 B) | Z[32][1032] bf16 (66048 B) |
//      Bs[512][32] bf16 swizzled (32768 B, doubles as small-scratch region)
__global__ __launch_bounds__(256) void fusedA(
    const float* __restrict__ wf, const float* __restrict__ of,
    const float* __restrict__ vg, const unsigned short* __restrict__ Bt, // owWt [512][1024]
    const float* __restrict__ ow_b,
    const float* __restrict__ tf, const float* __restrict__ im,
    const float* __restrict__ it, const float* __restrict__ fa,
    unsigned short* __restrict__ x5)
{
    __shared__ __align__(16) char smem[156608];
    float* Xs = (float*)smem;                              // [28][516]
    unsigned short* Z = (unsigned short*)(smem + 57792);   // [32][1032]
    char* BsB = smem + 123840;                             // [512][64B] swizzled
    float* sml = (float*)BsB;                              // small scratch (time-shared)

    const int b = blockIdx.x;
    const int tid = threadIdx.x;
    const int lane = tid & 63;
    const int wid = tid >> 6;

    // ---- phase 0: load X (fp32) ----
    for (int idx = tid; idx < 28 * 128; idx += 256) {
        int n = idx >> 7, c = (idx & 127) * 4;
        const float* src = (n < 12) ? (wf + ((size_t)b * 12 + n) * 512)
                                    : (of + ((size_t)b * 16 + (n - 12)) * 512);
        *(float4*)&Xs[n * 516 + c] = *(const float4*)(src + c);
    }
    __syncthreads();

    // ---- phase 1: 112 score dots + alpha ----
    float* ss = sml;          // [28][2]
    float* sd = sml + 56;     // [28][2]
    float* alpha = sml + 112; // [16][2][13]
    for (int p = wid; p < 112; p += 4) {
        int n = p >> 2, t = p & 3;
        const float* vv = vg + t * 512;
        float s = 0.f;
#pragma unroll
        for (int j = 0; j < 8; ++j) s += Xs[n * 516 + lane + 64 * j] * vv[lane + 64 * j];
        for (int off = 32; off > 0; off >>= 1) s += __shfl_down(s, off, 64);
        if (lane == 0) { if (t < 2) ss[n * 2 + t] = s; else sd[n * 2 + t - 2] = s; }
    }
    __syncthreads();
    if (tid < 32) {
        int w = tid >> 1, h = tid & 1;
        float sdv = sd[(12 + w) * 2 + h];
        float e[13], mx = -1e30f;
        for (int j = 0; j < 12; ++j) { e[j] = lrelu02(ss[j * 2 + h] + sdv); mx = fmaxf(mx, e[j]); }
        e[12] = lrelu02(ss[(12 + w) * 2 + h] + sdv); mx = fmaxf(mx, e[12]);
        float den = 0.f;
        for (int j = 0; j < 13; ++j) { e[j] = expf(e[j] - mx); den += e[j]; }
        float inv = 1.f / den;
        for (int j = 0; j < 13; ++j) alpha[(w * 2 + h) * 13 + j] = e[j] * inv;
    }
    __syncthreads();

    // GEMM prologue B-loads (fly under phase 2)
    short8 rb[8];
#pragma unroll
    for (int i = 0; i < 8; ++i) {
        int idx = tid + i * 256;
        int row = idx >> 2, seg = idx & 3;
        rb[i] = *(const short8*)(Bt + (size_t)row * 1024 + seg * 8);
    }

    // ---- phase 2: build Z (bf16) ----
    for (int idx = tid; idx < 12 * 1024; idx += 256) {          // obj rows: [x|x]
        int n = idx >> 10, dd = idx & 1023;
        Z[n * 1032 + dd] = cvt_bf16(Xs[n * 516 + (dd & 511)]);
    }
    for (int c = tid; c < 1024; c += 256) {                     // word rows: aggregate
        int h = c >> 9, d = c & 511;
        float xr[12];
#pragma unroll
        for (int j = 0; j < 12; ++j) xr[j] = Xs[j * 516 + d];
#pragma unroll 4
        for (int w = 0; w < 16; ++w) {
            const float* alp = &alpha[(w * 2 + h) * 13];
            float a = alp[12] * Xs[(12 + w) * 516 + d];
#pragma unroll
            for (int j = 0; j < 12; ++j) a += alp[j] * xr[j];
            Z[(12 + w) * 1032 + c] = cvt_bf16(a);
        }
    }
    for (int idx = tid; idx < 4 * 1024; idx += 256)             // zero pad rows
        Z[(28 + (idx >> 10)) * 1032 + (idx & 1023)] = 0;
    __syncthreads();

    // ---- phase 3: hout = Z @ Bt^T + ow_b  (M=32, N=512, K=1024) ----
    // waves split N 4-ways: each wave 32 rows x 128 cols (MF=2, NF=8)
    const int wn = wid * 128;
    const int fr = lane & 15;
    const int slot = lane >> 4;           // k-quarter 0..3
    floatx4 acc[2][8];
#pragma unroll
    for (int i = 0; i < 2; ++i)
#pragma unroll
        for (int j = 0; j < 8; ++j) acc[i][j] = (floatx4){0.f, 0.f, 0.f, 0.f};

    for (int k0 = 0; k0 < 1024; k0 += 32) {
#pragma unroll
        for (int i = 0; i < 8; ++i) {     // staged regs -> Bs (XOR-swizzled slots)
            int idx = tid + i * 256;
            int row = idx >> 2, seg = idx & 3;
            int sw = seg ^ ((row >> 2) & 3);
            *(short8*)(BsB + row * 64 + sw * 16) = rb[i];
        }
        __syncthreads();
        if (k0 + 32 < 1024) {
#pragma unroll
            for (int i = 0; i < 8; ++i) { // prefetch next B-tile
                int idx = tid + i * 256;
                int row = idx >> 2, seg = idx & 3;
                rb[i] = *(const short8*)(Bt + (size_t)row * 1024 + (k0 + 32) + seg * 8);
            }
        }
        short8 af[2];
#pragma unroll
        for (int i = 0; i < 2; ++i)
            af[i] = *(const short8*)&Z[(i * 16 + fr) * 1032 + k0 + slot * 8];
#pragma unroll
        for (int j = 0; j < 8; ++j) {
            int row = wn + j * 16 + fr;
            int sw = slot ^ ((row >> 2) & 3);
            short8 bw = *(const short8*)(BsB + row * 64 + sw * 16);
#pragma unroll
            for (int i = 0; i < 2; ++i)
                acc[i][j] = __builtin_amdgcn_mfma_f32_16x16x32_bf16(af[i], bw, acc[i][j], 0, 0, 0);
        }
        __syncthreads();
    }

    // hout (+bias) into Xs region, rows 0..27
    const int fq = lane >> 4;
#pragma unroll
    for (int i = 0; i < 2; ++i) {
#pragma unroll
        for (int j = 0; j < 8; ++j) {
#pragma unroll
            for (int q = 0; q < 4; ++q) {
                int row = i * 16 + fq * 4 + q;
                int col = wn + j * 16 + fr;
                if (row < 28) Xs[row * 516 + col] = acc[i][j][q] + ow_b[col];
            }
        }
    }
    __syncthreads();

    // ---- phase 4: attn (12x16) + aligned + ind_norm -> x5 ----
    float* S = sml;          // [12][16]
    float* w16 = sml + 192;  // [16]
    float* al = sml + 208;   // [512]
    if (tid < 192) {
        int i = tid >> 4, j = tid & 15;
        float s = 0.f;
        for (int d = 0; d < 128; ++d) {
            float4 a = *(const float4*)&Xs[i * 516 + d * 4];
            float4 c = *(const float4*)&Xs[(12 + j) * 516 + d * 4];
            s += a.x * c.x + a.y * c.y + a.z * c.z + a.w * c.w;
        }
        S[i * 16 + j] = s;
    }
    __syncthreads();
    if (tid < 12) {
        float mx = -1e30f;
        for (int j = 0; j < 16; ++j) mx = fmaxf(mx, S[tid * 16 + j]);
        float den = 0.f;
        for (int j = 0; j < 16; ++j) { float p = expf(S[tid * 16 + j] - mx); S[tid * 16 + j] = p; den += p; }
        float inv = 1.f / den;
        for (int j = 0; j < 16; ++j) S[tid * 16 + j] *= inv;
    }
    __syncthreads();
    if (tid < 16) {
        float s = 0.f;
        for (int i = 0; i < 12; ++i) s += S[i * 16 + tid];
        w16[tid] = s * (1.f / 12.f);
    }
    __syncthreads();
    for (int d = tid; d < 512; d += 256) {
        float s = 0.f;
#pragma unroll
        for (int j = 0; j < 16; ++j) s += w16[j] * Xs[(12 + j) * 516 + d];
        al[d] = s;
    }
    __syncthreads();

    for (int f = wid; f < 5; f += 4) {
        const float* src = (f == 0) ? tf : (f == 1) ? im : (f == 2) ? it : (f == 3) ? fa : nullptr;
        float vals[8];
        float sum = 0.f, sq = 0.f;
#pragma unroll
        for (int j = 0; j < 8; ++j) {
            float v = (f < 4) ? src[(size_t)b * 512 + lane + 64 * j] : al[lane + 64 * j];
            vals[j] = v;
            sum += v;
            sq += v * v;
        }
#pragma unroll
        for (int off = 32; off > 0; off >>= 1) {
            sum += __shfl_xor(sum, off, 64);
            sq  += __shfl_xor(sq,  off, 64);
        }
        float v = (sum != 0.f) ? 1.f : 0.f;
        float nrm = fmaxf(sqrtf(sq + v * v), 1e-12f);
        float inv = 1.f / nrm;
        unsigned short* dst = x5 + ((size_t)b * 5 + f) * 544;
#pragma unroll
        for (int j = 0; j < 8; ++j) dst[lane + 64 * j] = cvt_bf16(vals[j] * inv);
        if (lane == 0) dst[512] = cvt_bf16(v * inv);
        else if (lane < 32) dst[512 + lane] = 0;
    }
}

// ---------------- GEMM v2: 1-barrier double-buffered pipeline ---------------
template <int BM, int BN, int RELU, int SPLITK>
__global__ __launch_bounds__(256) void gemm_v2(
    const unsigned short* __restrict__ A, int lda,
    const unsigned short* __restrict__ Bt, int ldbt,
    float* __restrict__ C, int ldc,
    int M, int N, int K,
    const float* __restrict__ bias)
{
    constexpr int WM = BM / 2, WN = BN / 2;
    constexpr int MF = WM / 16, NF = WN / 16;
    constexpr int CA = BM / 64, CB = BN / 64;

    __shared__ unsigned short As[2][BM][40];
    __shared__ unsigned short Bs[2][BN][40];

    const int tid = threadIdx.x;
    const int m0 = blockIdx.x * BM;
    const int n0 = blockIdx.y * BN;
    const int lane = tid & 63;
    const int wid = tid >> 6;
    const int wm = (wid & 1) * WM;
    const int wn = (wid >> 1) * WN;
    const int fr = lane & 15;
    const int kq = (lane >> 4) * 8;

    const int srow = tid >> 2;
    const int scol = (tid & 3) * 8;

    const int kchunk = K / SPLITK;
    const int kbeg = (SPLITK > 1) ? blockIdx.z * kchunk : 0;
    const int kend = kbeg + kchunk;
    if (SPLITK > 1) C += (size_t)blockIdx.z * M * ldc;

    short8 ra[CA], rb[CB];
#define LOADAB(K0)                                                                   \
    do {                                                                             \
        _Pragma("unroll")                                                            \
        for (int c = 0; c < CA; ++c)                                                 \
            ra[c] = *(const short8*)(A + (size_t)(m0 + srow + c * 64) * lda + (K0) + scol); \
        _Pragma("unroll")                                                            \
        for (int c = 0; c < CB; ++c)                                                 \
            rb[c] = *(const short8*)(Bt + (size_t)(n0 + srow + c * 64) * ldbt + (K0) + scol); \
    } while (0)

    LOADAB(kbeg);

    floatx4 acc[MF][NF];
#pragma unroll
    for (int i = 0; i < MF; ++i)
#pragma unroll
        for (int j = 0; j < NF; ++j) acc[i][j] = (floatx4){0.f, 0.f, 0.f, 0.f};

    int t = 0;
    for (int k0 = kbeg; k0 < kend; k0 += 32, t ^= 1) {
#pragma unroll
        for (int c = 0; c < CA; ++c) *(short8*)&As[t][srow + c * 64][scol] = ra[c];
#pragma unroll
        for (int c = 0; c < CB; ++c) *(short8*)&Bs[t][srow + c * 64][scol] = rb[c];
        __syncthreads();
        if (k0 + 32 < kend) LOADAB(k0 + 32);

        short8 af[MF], bw[NF];
#pragma unroll
        for (int i = 0; i < MF; ++i)
            af[i] = *(const short8*)&As[t][wm + i * 16 + fr][kq];
#pragma unroll
        for (int j = 0; j < NF; ++j)
            bw[j] = *(const short8*)&Bs[t][wn + j * 16 + fr][kq];
#pragma unroll
        for (int i = 0; i < MF; ++i)
#pragma unroll
            for (int j = 0; j < NF; ++j)
                acc[i][j] = __builtin_amdgcn_mfma_f32_16x16x32_bf16(
                    af[i], bw[j], acc[i][j], 0, 0, 0);
    }
#undef LOADAB

    const int fq = lane >> 4;
#pragma unroll
    for (int i = 0; i < MF; ++i) {
#pragma unroll
        for (int j = 0; j < NF; ++j) {
#pragma unroll
            for (int q = 0; q < 4; ++q) {
                int row = m0 + wm + i * 16 + fq * 4 + q;
                int col = n0 + wn + j * 16 + fr;
                float v = acc[i][j][q];
                if (SPLITK == 1 && bias) v += bias[col];
                if (RELU) v = fmaxf(v, 0.f);
                C[(size_t)row * ldc + col] = v;
            }
        }
    }
}

// ---------------- C2/C4: 5-node complete-graph GAT --------------------------
template <int RELU>
__global__ __launch_bounds__(256) void g5_gat(
    const float* __restrict__ Hg,
    const float* __restrict__ asrc, const float* __restrict__ adst,
    const float* __restrict__ bias, unsigned short* __restrict__ outp)
{
    const int b = blockIdx.x;
    __shared__ float ss[5], sd[5];
    __shared__ float alpha[5][5];

    const int tid = threadIdx.x;
    const int lane = tid & 63;
    const int wave = tid >> 6;
    const float* Hb = Hg + (size_t)b * 5 * 512;

    for (int p = wave; p < 10; p += 4) {
        int n = p >> 1, ty = p & 1;
        const float* hv = Hb + n * 512;
        const float* av = ty ? adst : asrc;
        float s = 0.f;
#pragma unroll
        for (int j = 0; j < 8; ++j) s += hv[lane + 64 * j] * av[lane + 64 * j];
        for (int off = 32; off > 0; off >>= 1) s += __shfl_down(s, off, 64);
        if (lane == 0) { if (ty) sd[n] = s; else ss[n] = s; }
    }
    __syncthreads();

    if (tid < 5) {
        int dn = tid;
        float e[5];
        float mx = -1e30f;
        for (int s = 0; s < 5; ++s) {
            e[s] = lrelu02(ss[s] + sd[dn]);
            mx = fmaxf(mx, e[s]);
        }
        float den = 0.f;
        for (int s = 0; s < 5; ++s) { e[s] = expf(e[s] - mx); den += e[s]; }
        float inv = 1.f / den;
        for (int s = 0; s < 5; ++s) alpha[dn][s] = e[s] * inv;
    }
    __syncthreads();

    for (int d = tid; d < 512; d += 256) {
        float h0 = Hb[0 * 512 + d], h1 = Hb[1 * 512 + d], h2 = Hb[2 * 512 + d];
        float h3 = Hb[3 * 512 + d], h4 = Hb[4 * 512 + d];
        float bd = bias[d];
#pragma unroll
        for (int dn = 0; dn < 5; ++dn) {
            float v = alpha[dn][0] * h0 + alpha[dn][1] * h1 + alpha[dn][2] * h2 +
                      alpha[dn][3] * h3 + alpha[dn][4] * h4 + bd;
            if (RELU) v = fmaxf(v, 0.f);
            outp[((size_t)b * 5 + dn) * 512 + d] = cvt_bf16(v);
        }
    }
}

// ---------------- final: relu(sum split-K parts + b1) @ m2 + b2 -------------
__global__ __launch_bounds__(64) void final2(
    const float* __restrict__ parts, const float* __restrict__ b1,
    const float* __restrict__ w, const float* __restrict__ bvec,
    float* __restrict__ out)
{
    const int b = blockIdx.x;
    const int lane = threadIdx.x;
    float a0 = 0.f, a1 = 0.f, a2 = 0.f;
#pragma unroll
    for (int j = 0; j < 8; ++j) {
        int d = lane + 64 * j;
        size_t o = (size_t)b * 512 + d;
        float x = parts[o] + parts[262144 + o] + parts[524288 + o] + parts[786432 + o] + b1[d];
        x = fmaxf(x, 0.f);
        a0 += x * w[d * 3 + 0];
        a1 += x * w[d * 3 + 1];
        a2 += x * w[d * 3 + 2];
    }
    for (int off = 32; off > 0; off >>= 1) {
        a0 += __shfl_down(a0, off, 64);
        a1 += __shfl_down(a1, off, 64);
        a2 += __shfl_down(a2, off, 64);
    }
    if (lane == 0) {
        out[b * 3 + 0] = a0 + bvec[0];
        out[b * 3 + 1] = a1 + bvec[1];
        out[b * 3 + 2] = a2 + bvec[2];
    }
}

extern "C" void kernel_launch(void* const* d_in, const int* in_sizes, int n_in,
                              void* d_out, int out_size, void* d_ws, size_t ws_size,
                              hipStream_t stream) {
    const float* text   = (const float*)d_in[0];
    const float* image  = (const float*)d_in[1];
    const float* imgtxt = (const float*)d_in[2];
    const float* face   = (const float*)d_in[3];
    const float* word   = (const float*)d_in[4];
    const float* obj    = (const float*)d_in[5];
    const float* ow_W    = (const float*)d_in[6];
    const float* ow_asrc = (const float*)d_in[7];
    const float* ow_adst = (const float*)d_in[8];
    const float* ow_b    = (const float*)d_in[9];
    const float* g1_W    = (const float*)d_in[10];
    const float* g1_asrc = (const float*)d_in[11];
    const float* g1_adst = (const float*)d_in[12];
    const float* g1_b    = (const float*)d_in[13];
    const float* g2_W    = (const float*)d_in[14];
    const float* g2_asrc = (const float*)d_in[15];
    const float* g2_adst = (const float*)d_in[16];
    const float* g2_b    = (const float*)d_in[17];
    const float* m1_W    = (const float*)d_in[18];
    const float* m1_b    = (const float*)d_in[19];
    const float* m2_W    = (const float*)d_in[20];
    const float* m2_b    = (const float*)d_in[21];

    float* ws = (float*)d_ws;
    float* vg = ws;                                         // 2048 f
    unsigned short* owWt = (unsigned short*)(ws + 2048);    // 512x1024
    unsigned short* g1Wt = owWt + 524288;                   // 512x544
    unsigned short* g2Wt = g1Wt + 278528;                   // 512x512
    unsigned short* m1Wt = g2Wt + 262144;                   // 512x2560
    unsigned short* x5b  = m1Wt + 1310720;                  // 2560x544
    unsigned short* h1b  = x5b + 1392640;                   // 2560x512
    unsigned short* fsb  = h1b + 1310720;                   // 2560x512
    float* hg   = (float*)(fsb + 1310720);                  // 2560x512 f
    float* hidp = hg + 1310720;                             // 4x512x512 f

    // prep: vvec + all weight transposes
    prep<<<2448, 256, 0, stream>>>(ow_W, ow_asrc, ow_adst, g1_W, g2_W, m1_W,
                                   vg, owWt, g1Wt, g2Wt, m1Wt);

    // stage A fully fused (one block per sample)
    fusedA<<<B_SAMP, 256, 0, stream>>>(word, obj, vg, owWt, ow_b,
                                       text, image, imgtxt, face, x5b);

    // stage C
    gemm_v2<64, 64, 0, 1><<<dim3(40, 8), 256, 0, stream>>>(
        x5b, 544, g1Wt, 544, hg, 512, 2560, 512, 544, nullptr);
    g5_gat<1><<<B_SAMP, 256, 0, stream>>>(hg, g1_asrc, g1_adst, g1_b, h1b);
    gemm_v2<64, 64, 0, 1><<<dim3(40, 8), 256, 0, stream>>>(
        h1b, 512, g2Wt, 512, hg, 512, 2560, 512, 512, nullptr);
    g5_gat<0><<<B_SAMP, 256, 0, stream>>>(hg, g2_asrc, g2_adst, g2_b, fsb);

    // stage D (fsb viewed as [512][2560])
    gemm_v2<64, 64, 0, 4><<<dim3(8, 8, 4), 256, 0, stream>>>(
        fsb, 2560, m1Wt, 2560, hidp, 512, 512, 512, 2560, nullptr);
    final2<<<B_SAMP, 64, 0, stream>>>(hidp, m1_b, m2_W, m2_b, (float*)d_out);
}

// Round 7
// 132.038 us; speedup vs baseline: 1.1420x; 1.1420x over previous
//
#include <hip/hip_runtime.h>
#include <hip/hip_bf16.h>
#include <math.h>

// ---------------------------------------------------------------------------
// SentiGAT — round 6: fusedA with 1024 threads (16 waves, 4/SIMD).
//  prep  : vvec + all weight transposes (unchanged)
//  fusedA: X -> scores/alpha -> z(LDS bf16) -> in-LDS MFMA GEMM (z @ Wc)
//          -> hout(LDS fp32) -> attn softmax -> aligned -> ind_norm -> x5b
//  C1/C3 : MFMA GEMMs, C2/C4: 5-node GAT, D1: split-K MFMA, D2: final proj
// ---------------------------------------------------------------------------

#define B_SAMP 512

typedef short short8 __attribute__((ext_vector_type(8)));
typedef float floatx4 __attribute__((ext_vector_type(4)));

__device__ __forceinline__ float lrelu02(float x) { return x > 0.f ? x : 0.2f * x; }

__device__ __forceinline__ unsigned short cvt_bf16(float f) {
    union { float f; unsigned int u; } v; v.f = f;
    unsigned int u = v.u;
    return (unsigned short)((u + 0x7FFFu + ((u >> 16) & 1u)) >> 16);  // RNE
}

// ---------------- merged prep: ow_vvec + all weight transposes --------------
__global__ __launch_bounds__(256) void prep(
    const float* __restrict__ ow_W, const float* __restrict__ ow_asrc,
    const float* __restrict__ ow_adst,
    const float* __restrict__ g1_W, const float* __restrict__ g2_W,
    const float* __restrict__ m1_W,
    float* __restrict__ vg, unsigned short* __restrict__ owWt,
    unsigned short* __restrict__ g1Wt, unsigned short* __restrict__ g2Wt,
    unsigned short* __restrict__ m1Wt)
{
    __shared__ float T[32][33];
    const int tid = threadIdx.x;
    int bid = blockIdx.x;

    if (bid < 128) {
        const int lane = tid & 63;
        const int gw = bid * 4 + (tid >> 6);
        for (int idx = gw; idx < 2048; idx += 512) {
            int t = idx >> 9, k = idx & 511;
            const float* a = (t < 2) ? (ow_asrc + t * 512) : (ow_adst + (t - 2) * 512);
            const float* wr = ow_W + (size_t)k * 1024 + (t & 1) * 512;
            float s = 0.f;
#pragma unroll
            for (int j = 0; j < 8; ++j) s += wr[lane + 64 * j] * a[lane + 64 * j];
            for (int off = 32; off > 0; off >>= 1) s += __shfl_down(s, off, 64);
            if (lane == 0) vg[idx] = s;
        }
        return;
    }
    bid -= 128;
    const float* W; int ldw, K, Kpad, koff, ktiles; float scale; unsigned short* Wt;
    if (bid < 256)        { W = ow_W;       ldw = 1024; K = 512;  Kpad = 1024; koff = 0;   scale = 0.5f; Wt = owWt; ktiles = 16; }
    else if (bid < 512)   { bid -= 256;  W = ow_W + 512; ldw = 1024; K = 512;  Kpad = 1024; koff = 512; scale = 0.5f; Wt = owWt; ktiles = 16; }
    else if (bid < 784)   { bid -= 512;  W = g1_W; ldw = 512; K = 513;  Kpad = 544;  koff = 0; scale = 1.f; Wt = g1Wt; ktiles = 17; }
    else if (bid < 1040)  { bid -= 784;  W = g2_W; ldw = 512; K = 512;  Kpad = 512;  koff = 0; scale = 1.f; Wt = g2Wt; ktiles = 16; }
    else                  { bid -= 1040; W = m1_W; ldw = 512; K = 2560; Kpad = 2560; koff = 0; scale = 1.f; Wt = m1Wt; ktiles = 80; }
    const int k0 = (bid % ktiles) * 32;
    const int n0 = (bid / ktiles) * 32;
    {
        int kr = tid >> 3, nc = (tid & 7) * 4;
        float4 v = make_float4(0.f, 0.f, 0.f, 0.f);
        if (k0 + kr < K) v = *(const float4*)(W + (size_t)(k0 + kr) * ldw + n0 + nc);
        T[nc + 0][kr] = v.x * scale; T[nc + 1][kr] = v.y * scale;
        T[nc + 2][kr] = v.z * scale; T[nc + 3][kr] = v.w * scale;
    }
    __syncthreads();
    {
        int nr = tid >> 3, kc = (tid & 7) * 4;
        ushort4 w;
        w.x = cvt_bf16(T[nr][kc + 0]);
        w.y = cvt_bf16(T[nr][kc + 1]);
        w.z = cvt_bf16(T[nr][kc + 2]);
        w.w = cvt_bf16(T[nr][kc + 3]);
        *(ushort4*)(Wt + (size_t)(n0 + nr) * Kpad + koff + k0 + kc) = w;
    }
}

// ---------------- fusedA: one block per sample, 16 waves --------------------
// LDS: Xs[28][516] f32 (57792 B) | Z[32][1032] bf16 (66048 B) |
//      Bs[512][64B] swizzled (32768 B; low part doubles as small scratch)
__global__ __launch_bounds__(1024, 4) void fusedA(
    const float* __restrict__ wf, const float* __restrict__ of,
    const float* __restrict__ vg, const unsigned short* __restrict__ Bt, // owWt [512][1024]
    const float* __restrict__ ow_b,
    const float* __restrict__ tf, const float* __restrict__ im,
    const float* __restrict__ it, const float* __restrict__ fa,
    unsigned short* __restrict__ x5)
{
    __shared__ __align__(16) char smem[156608];
    float* Xs = (float*)smem;                              // [28][516]
    unsigned short* Z = (unsigned short*)(smem + 57792);   // [32][1032]
    char* BsB = smem + 123840;                             // [512][64B]
    float* sml = (float*)BsB;                              // scratch (time-shared)

    const int b = blockIdx.x;
    const int tid = threadIdx.x;
    const int lane = tid & 63;
    const int wid = tid >> 6;          // 0..15

    // ---- phase 0: load X (fp32) ----
    for (int idx = tid; idx < 28 * 128; idx += 1024) {
        int n = idx >> 7, c = (idx & 127) * 4;
        const float* src = (n < 12) ? (wf + ((size_t)b * 12 + n) * 512)
                                    : (of + ((size_t)b * 16 + (n - 12)) * 512);
        *(float4*)&Xs[n * 516 + c] = *(const float4*)(src + c);
    }
    __syncthreads();

    // ---- phase 1: 112 score dots + alpha ----
    float* ss = sml;          // [28][2]
    float* sd = sml + 56;     // [28][2]
    float* alpha = sml + 112; // [16][2][13]
    for (int p = wid; p < 112; p += 16) {
        int n = p >> 2, t = p & 3;
        const float* vv = vg + t * 512;
        float s = 0.f;
#pragma unroll
        for (int j = 0; j < 8; ++j) s += Xs[n * 516 + lane + 64 * j] * vv[lane + 64 * j];
        for (int off = 32; off > 0; off >>= 1) s += __shfl_down(s, off, 64);
        if (lane == 0) { if (t < 2) ss[n * 2 + t] = s; else sd[n * 2 + t - 2] = s; }
    }
    __syncthreads();
    if (tid < 32) {
        int w = tid >> 1, h = tid & 1;
        float sdv = sd[(12 + w) * 2 + h];
        float e[13], mx = -1e30f;
        for (int j = 0; j < 12; ++j) { e[j] = lrelu02(ss[j * 2 + h] + sdv); mx = fmaxf(mx, e[j]); }
        e[12] = lrelu02(ss[(12 + w) * 2 + h] + sdv); mx = fmaxf(mx, e[12]);
        float den = 0.f;
        for (int j = 0; j < 13; ++j) { e[j] = expf(e[j] - mx); den += e[j]; }
        float inv = 1.f / den;
        for (int j = 0; j < 13; ++j) alpha[(w * 2 + h) * 13 + j] = e[j] * inv;
    }
    __syncthreads();

    // GEMM prologue B-loads (fly under phase 2): 2 x b128 per thread
    short8 rb[2];
#pragma unroll
    for (int i = 0; i < 2; ++i) {
        int idx = tid + i * 1024;
        int row = idx >> 2, seg = idx & 3;
        rb[i] = *(const short8*)(Bt + (size_t)row * 1024 + seg * 8);
    }

    // ---- phase 2: build Z (bf16) ----
    for (int idx = tid; idx < 12 * 512; idx += 1024) {          // obj rows: [x|x], ushort2
        int n = idx >> 9, p = idx & 511;
        int d = (p * 2) & 511;
        ushort2 v;
        v.x = cvt_bf16(Xs[n * 516 + d]);
        v.y = cvt_bf16(Xs[n * 516 + d + 1]);
        *(ushort2*)&Z[n * 1032 + p * 2] = v;
    }
    {                                                            // word rows: aggregate
        int c = tid;
        int h = c >> 9, d = c & 511;
        float xr[12];
#pragma unroll
        for (int j = 0; j < 12; ++j) xr[j] = Xs[j * 516 + d];
#pragma unroll 4
        for (int w = 0; w < 16; ++w) {
            const float* alp = &alpha[(w * 2 + h) * 13];
            float a = alp[12] * Xs[(12 + w) * 516 + d];
#pragma unroll
            for (int j = 0; j < 12; ++j) a += alp[j] * xr[j];
            Z[(12 + w) * 1032 + c] = cvt_bf16(a);
        }
    }
    for (int idx = tid; idx < 4 * 512; idx += 1024)              // zero pad rows 28..31
        *(ushort2*)&Z[(28 + (idx >> 9)) * 1032 + (idx & 511) * 2] = make_ushort2(0, 0);
    __syncthreads();

    // ---- phase 3: hout = Z @ Bt^T + ow_b  (M=32, N=512, K=1024) ----
    // 16 waves x 32 cols each (MF=2, NF=2)
    const int wn = wid * 32;
    const int fr = lane & 15;
    const int slot = lane >> 4;           // k-quarter 0..3
    floatx4 acc[2][2];
#pragma unroll
    for (int i = 0; i < 2; ++i)
#pragma unroll
        for (int j = 0; j < 2; ++j) acc[i][j] = (floatx4){0.f, 0.f, 0.f, 0.f};

    for (int k0 = 0; k0 < 1024; k0 += 32) {
#pragma unroll
        for (int i = 0; i < 2; ++i) {     // staged regs -> Bs (XOR-swizzled slots)
            int idx = tid + i * 1024;
            int row = idx >> 2, seg = idx & 3;
            int sw = seg ^ ((row >> 2) & 3);
            *(short8*)(BsB + row * 64 + sw * 16) = rb[i];
        }
        __syncthreads();
        if (k0 + 32 < 1024) {
#pragma unroll
            for (int i = 0; i < 2; ++i) { // prefetch next B-tile
                int idx = tid + i * 1024;
                int row = idx >> 2, seg = idx & 3;
                rb[i] = *(const short8*)(Bt + (size_t)row * 1024 + (k0 + 32) + seg * 8);
            }
        }
        short8 af[2], bw[2];
#pragma unroll
        for (int i = 0; i < 2; ++i)
            af[i] = *(const short8*)&Z[(i * 16 + fr) * 1032 + k0 + slot * 8];
#pragma unroll
        for (int j = 0; j < 2; ++j) {
            int row = wn + j * 16 + fr;
            int sw = slot ^ ((row >> 2) & 3);
            bw[j] = *(const short8*)(BsB + row * 64 + sw * 16);
        }
#pragma unroll
        for (int i = 0; i < 2; ++i)
#pragma unroll
            for (int j = 0; j < 2; ++j)
                acc[i][j] = __builtin_amdgcn_mfma_f32_16x16x32_bf16(af[i], bw[j], acc[i][j], 0, 0, 0);
        __syncthreads();
    }

    // hout (+bias) into Xs region, rows 0..27
    const int fq = lane >> 4;
#pragma unroll
    for (int i = 0; i < 2; ++i) {
#pragma unroll
        for (int j = 0; j < 2; ++j) {
#pragma unroll
            for (int q = 0; q < 4; ++q) {
                int row = i * 16 + fq * 4 + q;
                int col = wn + j * 16 + fr;
                if (row < 28) Xs[row * 516 + col] = acc[i][j][q] + ow_b[col];
            }
        }
    }
    __syncthreads();

    // ---- phase 4: attn (12x16) + aligned + ind_norm -> x5 ----
    float* S = sml;          // [12][16]
    float* w16 = sml + 192;  // [16]
    float* al = sml + 208;   // [512]
    for (int p = wid; p < 192; p += 16) {   // wave-parallel dots
        int i = p >> 4, j = p & 15;
        const float* ua = &Xs[i * 516 + lane * 8];
        const float* uc = &Xs[(12 + j) * 516 + lane * 8];
        float s = 0.f;
#pragma unroll
        for (int d = 0; d < 8; ++d) s += ua[d] * uc[d];
        for (int off = 32; off > 0; off >>= 1) s += __shfl_down(s, off, 64);
        if (lane == 0) S[i * 16 + j] = s;
    }
    __syncthreads();
    if (tid < 12) {
        float mx = -1e30f;
        for (int j = 0; j < 16; ++j) mx = fmaxf(mx, S[tid * 16 + j]);
        float den = 0.f;
        for (int j = 0; j < 16; ++j) { float p = expf(S[tid * 16 + j] - mx); S[tid * 16 + j] = p; den += p; }
        float inv = 1.f / den;
        for (int j = 0; j < 16; ++j) S[tid * 16 + j] *= inv;
    }
    __syncthreads();
    if (tid < 16) {
        float s = 0.f;
        for (int i = 0; i < 12; ++i) s += S[i * 16 + tid];
        w16[tid] = s * (1.f / 12.f);
    }
    __syncthreads();
    if (tid < 512) {
        int d = tid;
        float s = 0.f;
#pragma unroll
        for (int j = 0; j < 16; ++j) s += w16[j] * Xs[(12 + j) * 516 + d];
        al[d] = s;
    }
    __syncthreads();

    for (int f = wid; f < 5; f += 16) {
        const float* src = (f == 0) ? tf : (f == 1) ? im : (f == 2) ? it : (f == 3) ? fa : nullptr;
        float vals[8];
        float sum = 0.f, sq = 0.f;
#pragma unroll
        for (int j = 0; j < 8; ++j) {
            float v = (f < 4) ? src[(size_t)b * 512 + lane + 64 * j] : al[lane + 64 * j];
            vals[j] = v;
            sum += v;
            sq += v * v;
        }
#pragma unroll
        for (int off = 32; off > 0; off >>= 1) {
            sum += __shfl_xor(sum, off, 64);
            sq  += __shfl_xor(sq,  off, 64);
        }
        float v = (sum != 0.f) ? 1.f : 0.f;
        float nrm = fmaxf(sqrtf(sq + v * v), 1e-12f);
        float inv = 1.f / nrm;
        unsigned short* dst = x5 + ((size_t)b * 5 + f) * 544;
#pragma unroll
        for (int j = 0; j < 8; ++j) dst[lane + 64 * j] = cvt_bf16(vals[j] * inv);
        if (lane == 0) dst[512] = cvt_bf16(v * inv);
        else if (lane < 32) dst[512 + lane] = 0;
    }
}

// ---------------- GEMM v2: 1-barrier double-buffered pipeline ---------------
template <int BM, int BN, int RELU, int SPLITK>
__global__ __launch_bounds__(256) void gemm_v2(
    const unsigned short* __restrict__ A, int lda,
    const unsigned short* __restrict__ Bt, int ldbt,
    float* __restrict__ C, int ldc,
    int M, int N, int K,
    const float* __restrict__ bias)
{
    constexpr int WM = BM / 2, WN = BN / 2;
    constexpr int MF = WM / 16, NF = WN / 16;
    constexpr int CA = BM / 64, CB = BN / 64;

    __shared__ unsigned short As[2][BM][40];
    __shared__ unsigned short Bs[2][BN][40];

    const int tid = threadIdx.x;
    const int m0 = blockIdx.x * BM;
    const int n0 = blockIdx.y * BN;
    const int lane = tid & 63;
    const int wid = tid >> 6;
    const int wm = (wid & 1) * WM;
    const int wn = (wid >> 1) * WN;
    const int fr = lane & 15;
    const int kq = (lane >> 4) * 8;

    const int srow = tid >> 2;
    const int scol = (tid & 3) * 8;

    const int kchunk = K / SPLITK;
    const int kbeg = (SPLITK > 1) ? blockIdx.z * kchunk : 0;
    const int kend = kbeg + kchunk;
    if (SPLITK > 1) C += (size_t)blockIdx.z * M * ldc;

    short8 ra[CA], rb[CB];
#define LOADAB(K0)                                                                   \
    do {                                                                             \
        _Pragma("unroll")                                                            \
        for (int c = 0; c < CA; ++c)                                                 \
            ra[c] = *(const short8*)(A + (size_t)(m0 + srow + c * 64) * lda + (K0) + scol); \
        _Pragma("unroll")                                                            \
        for (int c = 0; c < CB; ++c)                                                 \
            rb[c] = *(const short8*)(Bt + (size_t)(n0 + srow + c * 64) * ldbt + (K0) + scol); \
    } while (0)

    LOADAB(kbeg);

    floatx4 acc[MF][NF];
#pragma unroll
    for (int i = 0; i < MF; ++i)
#pragma unroll
        for (int j = 0; j < NF; ++j) acc[i][j] = (floatx4){0.f, 0.f, 0.f, 0.f};

    int t = 0;
    for (int k0 = kbeg; k0 < kend; k0 += 32, t ^= 1) {
#pragma unroll
        for (int c = 0; c < CA; ++c) *(short8*)&As[t][srow + c * 64][scol] = ra[c];
#pragma unroll
        for (int c = 0; c < CB; ++c) *(short8*)&Bs[t][srow + c * 64][scol] = rb[c];
        __syncthreads();
        if (k0 + 32 < kend) LOADAB(k0 + 32);

        short8 af[MF], bw[NF];
#pragma unroll
        for (int i = 0; i < MF; ++i)
            af[i] = *(const short8*)&As[t][wm + i * 16 + fr][kq];
#pragma unroll
        for (int j = 0; j < NF; ++j)
            bw[j] = *(const short8*)&Bs[t][wn + j * 16 + fr][kq];
#pragma unroll
        for (int i = 0; i < MF; ++i)
#pragma unroll
            for (int j = 0; j < NF; ++j)
                acc[i][j] = __builtin_amdgcn_mfma_f32_16x16x32_bf16(
                    af[i], bw[j], acc[i][j], 0, 0, 0);
    }
#undef LOADAB

    const int fq = lane >> 4;
#pragma unroll
    for (int i = 0; i < MF; ++i) {
#pragma unroll
        for (int j = 0; j < NF; ++j) {
#pragma unroll
            for (int q = 0; q < 4; ++q) {
                int row = m0 + wm + i * 16 + fq * 4 + q;
                int col = n0 + wn + j * 16 + fr;
                float v = acc[i][j][q];
                if (SPLITK == 1 && bias) v += bias[col];
                if (RELU) v = fmaxf(v, 0.f);
                C[(size_t)row * ldc + col] = v;
            }
        }
    }
}

// ---------------- C2/C4: 5-node complete-graph GAT --------------------------
template <int RELU>
__global__ __launch_bounds__(256) void g5_gat(
    const float* __restrict__ Hg,
    const float* __restrict__ asrc, const float* __restrict__ adst,
    const float* __restrict__ bias, unsigned short* __restrict__ outp)
{
    const int b = blockIdx.x;
    __shared__ float ss[5], sd[5];
    __shared__ float alpha[5][5];

    const int tid = threadIdx.x;
    const int lane = tid & 63;
    const int wave = tid >> 6;
    const float* Hb = Hg + (size_t)b * 5 * 512;

    for (int p = wave; p < 10; p += 4) {
        int n = p >> 1, ty = p & 1;
        const float* hv = Hb + n * 512;
        const float* av = ty ? adst : asrc;
        float s = 0.f;
#pragma unroll
        for (int j = 0; j < 8; ++j) s += hv[lane + 64 * j] * av[lane + 64 * j];
        for (int off = 32; off > 0; off >>= 1) s += __shfl_down(s, off, 64);
        if (lane == 0) { if (ty) sd[n] = s; else ss[n] = s; }
    }
    __syncthreads();

    if (tid < 5) {
        int dn = tid;
        float e[5];
        float mx = -1e30f;
        for (int s = 0; s < 5; ++s) {
            e[s] = lrelu02(ss[s] + sd[dn]);
            mx = fmaxf(mx, e[s]);
        }
        float den = 0.f;
        for (int s = 0; s < 5; ++s) { e[s] = expf(e[s] - mx); den += e[s]; }
        float inv = 1.f / den;
        for (int s = 0; s < 5; ++s) alpha[dn][s] = e[s] * inv;
    }
    __syncthreads();

    for (int d = tid; d < 512; d += 256) {
        float h0 = Hb[0 * 512 + d], h1 = Hb[1 * 512 + d], h2 = Hb[2 * 512 + d];
        float h3 = Hb[3 * 512 + d], h4 = Hb[4 * 512 + d];
        float bd = bias[d];
#pragma unroll
        for (int dn = 0; dn < 5; ++dn) {
            float v = alpha[dn][0] * h0 + alpha[dn][1] * h1 + alpha[dn][2] * h2 +
                      alpha[dn][3] * h3 + alpha[dn][4] * h4 + bd;
            if (RELU) v = fmaxf(v, 0.f);
            outp[((size_t)b * 5 + dn) * 512 + d] = cvt_bf16(v);
        }
    }
}

// ---------------- final: relu(sum split-K parts + b1) @ m2 + b2 -------------
__global__ __launch_bounds__(64) void final2(
    const float* __restrict__ parts, const float* __restrict__ b1,
    const float* __restrict__ w, const float* __restrict__ bvec,
    float* __restrict__ out)
{
    const int b = blockIdx.x;
    const int lane = threadIdx.x;
    float a0 = 0.f, a1 = 0.f, a2 = 0.f;
#pragma unroll
    for (int j = 0; j < 8; ++j) {
        int d = lane + 64 * j;
        size_t o = (size_t)b * 512 + d;
        float x = parts[o] + parts[262144 + o] + parts[524288 + o] + parts[786432 + o] + b1[d];
        x = fmaxf(x, 0.f);
        a0 += x * w[d * 3 + 0];
        a1 += x * w[d * 3 + 1];
        a2 += x * w[d * 3 + 2];
    }
    for (int off = 32; off > 0; off >>= 1) {
        a0 += __shfl_down(a0, off, 64);
        a1 += __shfl_down(a1, off, 64);
        a2 += __shfl_down(a2, off, 64);
    }
    if (lane == 0) {
        out[b * 3 + 0] = a0 + bvec[0];
        out[b * 3 + 1] = a1 + bvec[1];
        out[b * 3 + 2] = a2 + bvec[2];
    }
}

extern "C" void kernel_launch(void* const* d_in, const int* in_sizes, int n_in,
                              void* d_out, int out_size, void* d_ws, size_t ws_size,
                              hipStream_t stream) {
    const float* text   = (const float*)d_in[0];
    const float* image  = (const float*)d_in[1];
    const float* imgtxt = (const float*)d_in[2];
    const float* face   = (const float*)d_in[3];
    const float* word   = (const float*)d_in[4];
    const float* obj    = (const float*)d_in[5];
    const float* ow_W    = (const float*)d_in[6];
    const float* ow_asrc = (const float*)d_in[7];
    const float* ow_adst = (const float*)d_in[8];
    const float* ow_b    = (const float*)d_in[9];
    const float* g1_W    = (const float*)d_in[10];
    const float* g1_asrc = (const float*)d_in[11];
    const float* g1_adst = (const float*)d_in[12];
    const float* g1_b    = (const float*)d_in[13];
    const float* g2_W    = (const float*)d_in[14];
    const float* g2_asrc = (const float*)d_in[15];
    const float* g2_adst = (const float*)d_in[16];
    const float* g2_b    = (const float*)d_in[17];
    const float* m1_W    = (const float*)d_in[18];
    const float* m1_b    = (const float*)d_in[19];
    const float* m2_W    = (const float*)d_in[20];
    const float* m2_b    = (const float*)d_in[21];

    float* ws = (float*)d_ws;
    float* vg = ws;                                         // 2048 f
    unsigned short* owWt = (unsigned short*)(ws + 2048);    // 512x1024
    unsigned short* g1Wt = owWt + 524288;                   // 512x544
    unsigned short* g2Wt = g1Wt + 278528;                   // 512x512
    unsigned short* m1Wt = g2Wt + 262144;                   // 512x2560
    unsigned short* x5b  = m1Wt + 1310720;                  // 2560x544
    unsigned short* h1b  = x5b + 1392640;                   // 2560x512
    unsigned short* fsb  = h1b + 1310720;                   // 2560x512
    float* hg   = (float*)(fsb + 1310720);                  // 2560x512 f
    float* hidp = hg + 1310720;                             // 4x512x512 f

    // prep: vvec + all weight transposes
    prep<<<2448, 256, 0, stream>>>(ow_W, ow_asrc, ow_adst, g1_W, g2_W, m1_W,
                                   vg, owWt, g1Wt, g2Wt, m1Wt);

    // stage A fully fused (one block per sample, 16 waves)
    fusedA<<<B_SAMP, 1024, 0, stream>>>(word, obj, vg, owWt, ow_b,
                                        text, image, imgtxt, face, x5b);

    // stage C
    gemm_v2<64, 64, 0, 1><<<dim3(40, 8), 256, 0, stream>>>(
        x5b, 544, g1Wt, 544, hg, 512, 2560, 512, 544, nullptr);
    g5_gat<1><<<B_SAMP, 256, 0, stream>>>(hg, g1_asrc, g1_adst, g1_b, h1b);
    gemm_v2<64, 64, 0, 1><<<dim3(40, 8), 256, 0, stream>>>(
        h1b, 512, g2Wt, 512, hg, 512, 2560, 512, 512, nullptr);
    g5_gat<0><<<B_SAMP, 256, 0, stream>>>(hg, g2_asrc, g2_adst, g2_b, fsb);

    // stage D (fsb viewed as [512][2560])
    gemm_v2<64, 64, 0, 4><<<dim3(8, 8, 4), 256, 0, stream>>>(
        fsb, 2560, m1Wt, 2560, hidp, 512, 512, 512, 2560, nullptr);
    final2<<<B_SAMP, 64, 0, stream>>>(hidp, m1_b, m2_W, m2_b, (float*)d_out);
}